// Round 4
// baseline (435.166 us; speedup 1.0000x reference)
//
#include <hip/hip_runtime.h>

// y[b,t,:] = x[b,t+1,:] - x[b,t,:]  for t < L-1 ; y[b,L-1,:] repeats last diff.
// B=16, L=8192, F=512, fp32.
//
// Persistent 2-deep software-pipelined version.
// Round-3 post-mortem: one-shot register-chained blocks (8192 blocks, 9-load
// burst -> wait -> store burst -> endpgm) reached only 3.65 TB/s request
// throughput vs 4.9 TB/s for the dumb flat kernel — bursty, phase-synchronized
// memory issue + block-turnover dead time. Fix: 2048 persistent blocks
// (8/CU, one resident generation), each sweeps 4 tiles with next-tile loads
// issued BEFORE current-tile compute+stores (sched_barrier-fenced), so every
// wave always has ~9 loads in flight. Traffic stays minimal (1.125x reads).

typedef float f32x4 __attribute__((ext_vector_type(4)));

#define L_     8192
#define F4_    128                  // float4 per timestep
#define TSTEP  8                    // timesteps per thread per tile
#define TBLK   16                   // timesteps per block-tile (2 halves)
#define NTILES 8192                 // B * L / TBLK = 16*512
#define NBLK   2048                 // persistent blocks (8 per CU)
#define TPB    (NTILES / NBLK)      // 4 tiles per block

__global__ __launch_bounds__(256) void diff1d_kernel(
    const f32x4* __restrict__ x, f32x4* __restrict__ y) {
    const int f4   = threadIdx.x & (F4_ - 1);   // 0..127
    const int half = threadIdx.x >> 7;          // 0/1, wave-uniform

    // tile id for sweep c: tile = c*NBLK + blockIdx.x  (each sweep is a
    // contiguous 64 MB region -> good DRAM/L2 locality within a sweep)
    auto tile_off = [&](int c, int& t0) -> size_t {
        int tile = c * NBLK + (int)blockIdx.x;
        int b    = tile >> 9;                   // / 512 tiles per batch
        int tb   = tile & 511;
        t0 = tb * TBLK + half * TSTEP;
        return ((size_t)b << 20) + (size_t)t0 * F4_ + f4;
    };

    auto load_tile = [&](const f32x4* xp, int t0, f32x4 (&v)[TSTEP + 1]) {
#pragma unroll
        for (int k = 0; k < TSTEP; ++k)
            v[k] = xp[k * F4_];
        if (t0 + TSTEP < L_)                    // uniform; only last tile skips
            v[TSTEP] = xp[TSTEP * F4_];
    };

    auto store_tile = [&](f32x4* yp, int t0, f32x4 (&v)[TSTEP + 1]) {
#pragma unroll
        for (int k = 0; k < TSTEP; ++k) {
            f32x4 d;
            if (t0 + k < L_ - 1) d = v[k + 1] - v[k];   // forward diff
            else                 d = v[k] - v[k - 1];   // t==L-1: repeat
            yp[k * F4_] = d;
        }
    };

    f32x4 v[2][TSTEP + 1];                      // double buffer (static idx
                                                // after full unroll)
    int t0_0;
    size_t off0 = tile_off(0, t0_0);
    load_tile(x + off0, t0_0, v[0]);

#pragma unroll
    for (int c = 0; c < TPB; ++c) {
        // ---- issue next tile's 9 loads (overlap current compute+stores) ----
        if (c + 1 < TPB) {
            int t0n;
            size_t offn = tile_off(c + 1, t0n);
            load_tile(x + offn, t0n, v[(c + 1) & 1]);
        }
        // fence: stores below must not hoist above the prefetch loads, and
        // the prefetch must not sink into / past the store loop.
        __builtin_amdgcn_sched_barrier(0);

        // ---- compute + store current tile ----
        int t0c;
        size_t offc = tile_off(c, t0c);
        store_tile(y + offc, t0c, v[c & 1]);
        __builtin_amdgcn_sched_barrier(0);
    }
}

extern "C" void kernel_launch(void* const* d_in, const int* in_sizes, int n_in,
                              void* d_out, int out_size, void* d_ws, size_t ws_size,
                              hipStream_t stream) {
    const f32x4* x = (const f32x4*)d_in[0];
    f32x4* y = (f32x4*)d_out;
    (void)in_sizes; (void)n_in; (void)out_size; (void)d_ws; (void)ws_size;

    diff1d_kernel<<<NBLK, 256, 0, stream>>>(x, y);
}